// Round 3
// baseline (363.632 us; speedup 1.0000x reference)
//
#include <hip/hip_runtime.h>

#define D 64          // node/edge feature dim
#define HID 128       // hidden dim
#define MLPB 512      // MLP block size (8 waves)
#define WPB 8         // waves per block
#define NB 4          // nodes per wave-batch
#define WIN_SHIFT 13  // 8192 nodes per place-window -> ~1MB elist window (L2-resident)

// ---------------------------------------------------------------------------
// Index dtype: reference says int64, harness may deliver int32. Probe high
// words of the first 64 pairs: int64 -> all zero (ids < 50000); int32 ->
// random node ids, P(all zero) ~ (2e-5)^64 ~ 0. Deterministic.
// ---------------------------------------------------------------------------
__device__ __forceinline__ bool detect_i64(const int* __restrict__ eidx, int lane)
{
    int probe = eidx[2 * lane + 1];
    return (__ballot(probe == 0) == ~0ULL);
}

// ---------- CSR build ------------------------------------------------------
// Entry t in [0, 2E): t < E -> src of edge t; t >= E -> dst of edge t-E.
__global__ __launch_bounds__(256)
void csr_hist(const int* __restrict__ eidx, int* __restrict__ counts, int n_edges)
{
    int t = blockIdx.x * 256 + threadIdx.x;
    bool is64 = detect_i64(eidx, threadIdx.x & 63);
    if (t >= 2 * n_edges) return;
    int idx = is64 ? eidx[2 * (size_t)t] : eidx[t];
    atomicAdd(&counts[idx], 1);
}

__global__ __launch_bounds__(256)
void csr_blocksum(const int* __restrict__ counts, int* __restrict__ bsum, int n)
{
    int i = blockIdx.x * 256 + threadIdx.x;
    int v = (i < n) ? counts[i] : 0;
    #pragma unroll
    for (int o = 1; o < 64; o <<= 1) v += __shfl_xor(v, o);
    __shared__ int ws[4];
    if ((threadIdx.x & 63) == 0) ws[threadIdx.x >> 6] = v;
    __syncthreads();
    if (threadIdx.x == 0) bsum[blockIdx.x] = ws[0] + ws[1] + ws[2] + ws[3];
}

__global__ __launch_bounds__(256)
void csr_scan_bsum(int* __restrict__ bsum, int nb)
{
    __shared__ int s[256];
    int i = threadIdx.x;
    int v = (i < nb) ? bsum[i] : 0;
    s[i] = v; __syncthreads();
    #pragma unroll
    for (int o = 1; o < 256; o <<= 1) {
        int t = (i >= o) ? s[i - o] : 0;
        __syncthreads();
        s[i] += t;
        __syncthreads();
    }
    if (i < nb) bsum[i] = s[i] - v;   // exclusive
}

__global__ __launch_bounds__(256)
void csr_scan_final(const int* __restrict__ counts, const int* __restrict__ bsum,
                    int* __restrict__ offsets, int* __restrict__ cursor, int n)
{
    __shared__ int s[256];
    int i = blockIdx.x * 256 + threadIdx.x;
    int v = (i < n) ? counts[i] : 0;
    s[threadIdx.x] = v; __syncthreads();
    #pragma unroll
    for (int o = 1; o < 256; o <<= 1) {
        int t = (threadIdx.x >= o) ? s[threadIdx.x - o] : 0;
        __syncthreads();
        s[threadIdx.x] += t;
        __syncthreads();
    }
    int excl = s[threadIdx.x] - v + bsum[blockIdx.x];
    if (i < n) { offsets[i] = excl; cursor[i] = excl; }
    if (i == n - 1) offsets[n] = excl + v;   // total = 2E
}

// Windowed place: blockIdx.y selects an 8192-node window; only entries whose
// node is in the window are committed this pass. The window's elist range
// (~1MB) stays L2-resident so the 16 random 4B-writes per line coalesce in
// cache and flush once. Window passes > 0 re-read eidx from L3.
__global__ __launch_bounds__(256)
void csr_place_win(const int* __restrict__ eidx, int* __restrict__ cursor,
                   int* __restrict__ elist, int n_edges)
{
    const int lo = blockIdx.y << WIN_SHIFT;
    const int hi = lo + (1 << WIN_SHIFT);
    const int E2 = 2 * n_edges;
    bool is64 = detect_i64(eidx, threadIdx.x & 63);
    const int stride = gridDim.x * 256;
    for (int t = blockIdx.x * 256 + threadIdx.x; t < E2; t += stride) {
        int idx = is64 ? eidx[2 * (size_t)t] : eidx[t];
        if (idx >= lo && idx < hi) {
            int eid = (t < n_edges) ? t : t - n_edges;
            int p = atomicAdd(&cursor[idx], 1);
            elist[p] = eid;
        }
    }
}

// ---------- fused gather + MLP --------------------------------------------
// Per wave-batch of NB=4 nodes: gather agg[n] = sum of incident x_edge rows
// (edge ids are wave-uniform -> scalar loads; row reads are 256B coalesced,
// 8-deep ILP), stage concat(x_node, agg) into LDS as float4-over-nodes, then
// 2-layer MLP with W1/W2 staged in LDS. agg never hits global memory.
__global__ __launch_bounds__(MLPB, 1)
void nb_fused(const float* __restrict__ x_node, const float* __restrict__ x_edge,
              const int* __restrict__ offsets, const int* __restrict__ elist,
              const float* __restrict__ W1, const float* __restrict__ b1,
              const float* __restrict__ W2, const float* __restrict__ b2,
              float* __restrict__ out, int n_nodes)
{
    __shared__ float sW1[HID * HID];     // 64 KB
    __shared__ float sW2[HID * D];       // 32 KB
    __shared__ float sb1[HID];
    __shared__ float sb2[D];
    __shared__ float4 s_in[WPB][128];    // 16 KB
    __shared__ float4 s_h[WPB][128];     // 16 KB

    {
        const float4* W14 = (const float4*)W1;
        float4* sW14 = (float4*)sW1;
        #pragma unroll
        for (int i = 0; i < 8; ++i)
            sW14[threadIdx.x + i * MLPB] = W14[threadIdx.x + i * MLPB];
        const float4* W24 = (const float4*)W2;
        float4* sW24 = (float4*)sW2;
        #pragma unroll
        for (int i = 0; i < 4; ++i)
            sW24[threadIdx.x + i * MLPB] = W24[threadIdx.x + i * MLPB];
        if (threadIdx.x < 128) sb1[threadIdx.x] = b1[threadIdx.x];
        else if (threadIdx.x < 192) sb2[threadIdx.x - 128] = b2[threadIdx.x - 128];
    }
    __syncthreads();

    const int wave = threadIdx.x >> 6;
    const int lane = threadIdx.x & 63;
    const int group = blockIdx.x * WPB + wave;
    const int ngroups = gridDim.x * WPB;
    const int nbatches = (n_nodes + NB - 1) / NB;
    const float2* sW1_2 = (const float2*)sW1;

    for (int g = group; g < nbatches; g += ngroups) {
        const int n0 = g * NB;

        // ---- gather + stage inputs ----
        float4 vx, va;
        #pragma unroll
        for (int b = 0; b < NB; ++b) {
            const int n = n0 + b;
            const bool ok = (n < n_nodes);
            ((float*)&vx)[b] = ok ? x_node[(size_t)n * D + lane] : 0.f;
            float acc = 0.f;
            if (ok) {
                const int beg = offsets[n], end = offsets[n + 1];
                int i = beg;
                for (; i + 8 <= end; i += 8) {
                    int e0 = elist[i],     e1 = elist[i + 1];
                    int e2 = elist[i + 2], e3 = elist[i + 3];
                    int e4 = elist[i + 4], e5 = elist[i + 5];
                    int e6 = elist[i + 6], e7 = elist[i + 7];
                    float v0 = x_edge[(size_t)e0 * D + lane];
                    float v1 = x_edge[(size_t)e1 * D + lane];
                    float v2 = x_edge[(size_t)e2 * D + lane];
                    float v3 = x_edge[(size_t)e3 * D + lane];
                    float v4 = x_edge[(size_t)e4 * D + lane];
                    float v5 = x_edge[(size_t)e5 * D + lane];
                    float v6 = x_edge[(size_t)e6 * D + lane];
                    float v7 = x_edge[(size_t)e7 * D + lane];
                    acc += ((v0 + v1) + (v2 + v3)) + ((v4 + v5) + (v6 + v7));
                }
                for (; i < end; ++i) acc += x_edge[(size_t)elist[i] * D + lane];
            }
            ((float*)&va)[b] = acc;
        }
        s_in[wave][lane] = vx;
        s_in[wave][64 + lane] = va;
        __builtin_amdgcn_wave_barrier();

        // ---- hidden layer: lane j -> hidden units 2j, 2j+1 for 4 nodes ----
        const float bh0 = sb1[2 * lane], bh1 = sb1[2 * lane + 1];
        float a0[NB], a1[NB];
        #pragma unroll
        for (int b = 0; b < NB; ++b) { a0[b] = bh0; a1[b] = bh1; }

        #pragma unroll 4
        for (int k = 0; k < 128; ++k) {
            const float4 a = s_in[wave][k];
            const float2 w = sW1_2[k * 64 + lane];
            #pragma unroll
            for (int b = 0; b < NB; ++b) {
                a0[b] = fmaf(((const float*)&a)[b], w.x, a0[b]);
                a1[b] = fmaf(((const float*)&a)[b], w.y, a1[b]);
            }
        }
        float4 h0v, h1v;
        #pragma unroll
        for (int b = 0; b < NB; ++b) {
            ((float*)&h0v)[b] = fmaxf(a0[b], 0.f);
            ((float*)&h1v)[b] = fmaxf(a1[b], 0.f);
        }
        s_h[wave][2 * lane]     = h0v;
        s_h[wave][2 * lane + 1] = h1v;
        __builtin_amdgcn_wave_barrier();

        // ---- output layer: lane j -> out[j] for 4 nodes ----
        const float bo = sb2[lane];
        float o[NB];
        #pragma unroll
        for (int b = 0; b < NB; ++b) o[b] = bo;
        #pragma unroll 4
        for (int hh = 0; hh < 128; ++hh) {
            const float4 hv = s_h[wave][hh];
            const float wv = sW2[hh * 64 + lane];
            #pragma unroll
            for (int b = 0; b < NB; ++b)
                o[b] = fmaf(((const float*)&hv)[b], wv, o[b]);
        }
        #pragma unroll
        for (int b = 0; b < NB; ++b) {
            const int n = n0 + b;
            if (n < n_nodes) out[(size_t)n * D + lane] = o[b];
        }
    }
}

// ---------- fallbacks (small ws) ------------------------------------------
__global__ __launch_bounds__(256)
void nb_scatter(const float* __restrict__ x_edge, const int* __restrict__ eidx,
                float* __restrict__ agg, int n_edges)
{
    long long t = (long long)blockIdx.x * 256 + threadIdx.x;
    int e = (int)(t >> 6);
    if (e >= n_edges) return;
    int d = (int)(t & 63);
    bool is64 = detect_i64(eidx, threadIdx.x & 63);
    int s, dd;
    if (is64) {
        s  = eidx[2 * (size_t)e];
        dd = eidx[2 * ((size_t)n_edges + (size_t)e)];
    } else {
        s  = eidx[e];
        dd = eidx[n_edges + e];
    }
    float v = x_edge[(size_t)e * D + d];
    unsafeAtomicAdd(&agg[(size_t)s * D + d], v);
    unsafeAtomicAdd(&agg[(size_t)dd * D + d], v);
}

__global__ __launch_bounds__(MLPB, 1)
void nb_mlp(const float* __restrict__ x_node, const float* __restrict__ agg,
            const float* __restrict__ W1, const float* __restrict__ b1,
            const float* __restrict__ W2, const float* __restrict__ b2,
            float* __restrict__ out, int n_nodes)
{
    __shared__ float sW1[HID * HID];
    __shared__ float sW2[HID * D];
    __shared__ float sb1[HID];
    __shared__ float sb2[D];
    __shared__ float4 s_in[WPB][128];
    __shared__ float4 s_h[WPB][128];

    {
        const float4* W14 = (const float4*)W1;
        float4* sW14 = (float4*)sW1;
        #pragma unroll
        for (int i = 0; i < 8; ++i)
            sW14[threadIdx.x + i * MLPB] = W14[threadIdx.x + i * MLPB];
        const float4* W24 = (const float4*)W2;
        float4* sW24 = (float4*)sW2;
        #pragma unroll
        for (int i = 0; i < 4; ++i)
            sW24[threadIdx.x + i * MLPB] = W24[threadIdx.x + i * MLPB];
        if (threadIdx.x < 128) sb1[threadIdx.x] = b1[threadIdx.x];
        else if (threadIdx.x < 192) sb2[threadIdx.x - 128] = b2[threadIdx.x - 128];
    }
    __syncthreads();

    const int wave = threadIdx.x >> 6;
    const int lane = threadIdx.x & 63;
    const int group = blockIdx.x * WPB + wave;
    const int ngroups = gridDim.x * WPB;
    const int nbatches = (n_nodes + NB - 1) / NB;
    const float2* sW1_2 = (const float2*)sW1;

    for (int g = group; g < nbatches; g += ngroups) {
        const int n0 = g * NB;
        float4 vx, va;
        #pragma unroll
        for (int b = 0; b < NB; ++b) {
            const int n = n0 + b;
            const bool ok = (n < n_nodes);
            ((float*)&vx)[b] = ok ? x_node[(size_t)n * D + lane] : 0.f;
            ((float*)&va)[b] = ok ? agg[(size_t)n * D + lane] : 0.f;
        }
        s_in[wave][lane] = vx;
        s_in[wave][64 + lane] = va;
        __builtin_amdgcn_wave_barrier();

        const float bh0 = sb1[2 * lane], bh1 = sb1[2 * lane + 1];
        float a0[NB], a1[NB];
        #pragma unroll
        for (int b = 0; b < NB; ++b) { a0[b] = bh0; a1[b] = bh1; }
        #pragma unroll 4
        for (int k = 0; k < 128; ++k) {
            const float4 a = s_in[wave][k];
            const float2 w = sW1_2[k * 64 + lane];
            #pragma unroll
            for (int b = 0; b < NB; ++b) {
                a0[b] = fmaf(((const float*)&a)[b], w.x, a0[b]);
                a1[b] = fmaf(((const float*)&a)[b], w.y, a1[b]);
            }
        }
        float4 h0v, h1v;
        #pragma unroll
        for (int b = 0; b < NB; ++b) {
            ((float*)&h0v)[b] = fmaxf(a0[b], 0.f);
            ((float*)&h1v)[b] = fmaxf(a1[b], 0.f);
        }
        s_h[wave][2 * lane]     = h0v;
        s_h[wave][2 * lane + 1] = h1v;
        __builtin_amdgcn_wave_barrier();

        const float bo = sb2[lane];
        float o[NB];
        #pragma unroll
        for (int b = 0; b < NB; ++b) o[b] = bo;
        #pragma unroll 4
        for (int hh = 0; hh < 128; ++hh) {
            const float4 hv = s_h[wave][hh];
            const float wv = sW2[hh * 64 + lane];
            #pragma unroll
            for (int b = 0; b < NB; ++b)
                o[b] = fmaf(((const float*)&hv)[b], wv, o[b]);
        }
        #pragma unroll
        for (int b = 0; b < NB; ++b) {
            const int n = n0 + b;
            if (n < n_nodes) out[(size_t)n * D + lane] = o[b];
        }
    }
}

// ---------------------------------------------------------------------------
extern "C" void kernel_launch(void* const* d_in, const int* in_sizes, int n_in,
                              void* d_out, int out_size, void* d_ws, size_t ws_size,
                              hipStream_t stream)
{
    const float* x_node = (const float*)d_in[0];
    const float* x_edge = (const float*)d_in[1];
    const int*   eidx   = (const int*)d_in[2];
    const float* W1     = (const float*)d_in[3];
    const float* b1     = (const float*)d_in[4];
    const float* W2     = (const float*)d_in[5];
    const float* b2     = (const float*)d_in[6];
    float* out = (float*)d_out;

    const int n_nodes = in_sizes[0] / D;     // 50000
    const int n_edges = in_sizes[2] / 2;     // 800000
    const int E2 = 2 * n_edges;

    // ws layout: offsets[N+1] | counts[N] | cursor[N] | bsum[256] | elist[2E]
    const size_t need = ((size_t)(n_nodes + 1) + n_nodes + n_nodes + 256 + E2) * 4;

    if (ws_size >= need) {
        int* offsets = (int*)d_ws;
        int* counts  = offsets + (n_nodes + 1);
        int* cursor  = counts + n_nodes;
        int* bsum    = cursor + n_nodes;
        int* elist   = bsum + 256;

        const int nscan = (n_nodes + 255) / 256;

        hipMemsetAsync(counts, 0, (size_t)n_nodes * 4, stream);
        csr_hist<<<(E2 + 255) / 256, 256, 0, stream>>>(eidx, counts, n_edges);
        csr_blocksum<<<nscan, 256, 0, stream>>>(counts, bsum, n_nodes);
        csr_scan_bsum<<<1, 256, 0, stream>>>(bsum, nscan);
        csr_scan_final<<<nscan, 256, 0, stream>>>(counts, bsum, offsets, cursor, n_nodes);

        const int n_windows = (n_nodes + (1 << WIN_SHIFT) - 1) >> WIN_SHIFT;  // 7
        csr_place_win<<<dim3(1024, n_windows), 256, 0, stream>>>(
            eidx, cursor, elist, n_edges);

        nb_fused<<<256, MLPB, 0, stream>>>(
            x_node, x_edge, offsets, elist, W1, b1, W2, b2, out, n_nodes);
    } else {
        float* agg = out;
        hipMemsetAsync(agg, 0, (size_t)n_nodes * D * sizeof(float), stream);
        long long threads = (long long)n_edges * 64;
        nb_scatter<<<(int)((threads + 255) / 256), 256, 0, stream>>>(
            x_edge, eidx, agg, n_edges);
        nb_mlp<<<256, MLPB, 0, stream>>>(x_node, agg, W1, b1, W2, b2, out, n_nodes);
    }
}

// Round 4
// 315.744 us; speedup vs baseline: 1.1517x; 1.1517x over previous
//
#include <hip/hip_runtime.h>

#define D 64          // node/edge feature dim
#define HID 128       // hidden dim
#define MLPB 1024     // MLP block size (16 waves)
#define WPB 16        // waves per MLP block
#define NB 4          // nodes per wave-batch
#define WIN_SHIFT 13  // 8192 nodes per place-window -> ~1MB elist window (L2-resident)

// ---------------------------------------------------------------------------
// Index dtype: reference says int64, harness may deliver int32. Probe high
// words of the first 64 pairs: int64 -> all zero (ids < 50000); int32 ->
// random node ids, P(all zero) ~ (2e-5)^64 ~ 0. Deterministic.
// ---------------------------------------------------------------------------
__device__ __forceinline__ bool detect_i64(const int* __restrict__ eidx, int lane)
{
    int probe = eidx[2 * lane + 1];
    return (__ballot(probe == 0) == ~0ULL);
}

// ---------- CSR build ------------------------------------------------------
// Entry t in [0, 2E): t < E -> src of edge t; t >= E -> dst of edge t-E.
// Optionally writes decoded node ids to nid[] (tier A) for cheap re-scans.
__global__ __launch_bounds__(256)
void csr_hist(const int* __restrict__ eidx, int* __restrict__ counts,
              int* __restrict__ nid, int write_nid, int n_edges)
{
    int t = blockIdx.x * 256 + threadIdx.x;
    bool is64 = detect_i64(eidx, threadIdx.x & 63);
    if (t >= 2 * n_edges) return;
    int idx = is64 ? eidx[2 * (size_t)t] : eidx[t];
    if (write_nid) nid[t] = idx;
    atomicAdd(&counts[idx], 1);
}

__global__ __launch_bounds__(256)
void csr_blocksum(const int* __restrict__ counts, int* __restrict__ bsum, int n)
{
    int i = blockIdx.x * 256 + threadIdx.x;
    int v = (i < n) ? counts[i] : 0;
    #pragma unroll
    for (int o = 1; o < 64; o <<= 1) v += __shfl_xor(v, o);
    __shared__ int ws[4];
    if ((threadIdx.x & 63) == 0) ws[threadIdx.x >> 6] = v;
    __syncthreads();
    if (threadIdx.x == 0) bsum[blockIdx.x] = ws[0] + ws[1] + ws[2] + ws[3];
}

__global__ __launch_bounds__(256)
void csr_scan_bsum(int* __restrict__ bsum, int nb)
{
    __shared__ int s[256];
    int i = threadIdx.x;
    int v = (i < nb) ? bsum[i] : 0;
    s[i] = v; __syncthreads();
    #pragma unroll
    for (int o = 1; o < 256; o <<= 1) {
        int t = (i >= o) ? s[i - o] : 0;
        __syncthreads();
        s[i] += t;
        __syncthreads();
    }
    if (i < nb) bsum[i] = s[i] - v;   // exclusive
}

__global__ __launch_bounds__(256)
void csr_scan_final(const int* __restrict__ counts, const int* __restrict__ bsum,
                    int* __restrict__ offsets, int* __restrict__ cursor, int n)
{
    __shared__ int s[256];
    int i = blockIdx.x * 256 + threadIdx.x;
    int v = (i < n) ? counts[i] : 0;
    s[threadIdx.x] = v; __syncthreads();
    #pragma unroll
    for (int o = 1; o < 256; o <<= 1) {
        int t = (threadIdx.x >= o) ? s[threadIdx.x - o] : 0;
        __syncthreads();
        s[threadIdx.x] += t;
        __syncthreads();
    }
    int excl = s[threadIdx.x] - v + bsum[blockIdx.x];
    if (i < n) { offsets[i] = excl; cursor[i] = excl; }
    if (i == n - 1) offsets[n] = excl + v;   // total = 2E
}

// Windowed place: blockIdx.y selects an 8192-node window; the window's elist
// range (~1MB) stays L2-resident so the 16 random 4B-writes per line coalesce
// in cache and flush once. Tier A reads pre-decoded nid[] (6.4MB/pass, cached);
// tier B decodes from eidx each pass.
__global__ __launch_bounds__(256)
void csr_place_win(const int* __restrict__ eidx, const int* __restrict__ nid,
                   int use_nid, int* __restrict__ cursor,
                   int* __restrict__ elist, int n_edges)
{
    const int lo = blockIdx.y << WIN_SHIFT;
    const int hi = lo + (1 << WIN_SHIFT);
    const int E2 = 2 * n_edges;
    bool is64 = use_nid ? false : detect_i64(eidx, threadIdx.x & 63);
    const int stride = gridDim.x * 256;
    for (int t = blockIdx.x * 256 + threadIdx.x; t < E2; t += stride) {
        int idx = use_nid ? nid[t] : (is64 ? eidx[2 * (size_t)t] : eidx[t]);
        if (idx >= lo && idx < hi) {
            int eid = (t < n_edges) ? t : t - n_edges;
            int p = atomicAdd(&cursor[idx], 1);
            elist[p] = eid;
        }
    }
}

// ---------- gather: agg[n] = sum over incident edges of x_edge[e] ----------
// One wave per node. 16 lanes x float4 cover one 256B edge row; 4 row slots
// (lane>>4) run in parallel, 4x unrolled -> 16 edges in flight per wave.
// No LDS, low VGPR -> full occupancy for latency hiding.
__global__ __launch_bounds__(256)
void csr_gather4(const float* __restrict__ x_edge, const int* __restrict__ offsets,
                 const int* __restrict__ elist, float* __restrict__ agg, int n_nodes)
{
    const int w = (blockIdx.x * 256 + threadIdx.x) >> 6;
    if (w >= n_nodes) return;
    const int lane = threadIdx.x & 63;
    const int sub = lane >> 4;       // row slot 0..3
    const int q   = lane & 15;       // float4 index within row
    const float4* __restrict__ xe4 = (const float4*)x_edge;

    const int beg = offsets[w], end = offsets[w + 1];
    float4 acc = make_float4(0.f, 0.f, 0.f, 0.f);

    int i = beg + sub;
    for (; i + 12 < end; i += 16) {
        int e0 = elist[i];
        int e1 = elist[i + 4];
        int e2 = elist[i + 8];
        int e3 = elist[i + 12];
        float4 v0 = xe4[(size_t)e0 * 16 + q];
        float4 v1 = xe4[(size_t)e1 * 16 + q];
        float4 v2 = xe4[(size_t)e2 * 16 + q];
        float4 v3 = xe4[(size_t)e3 * 16 + q];
        acc.x += (v0.x + v1.x) + (v2.x + v3.x);
        acc.y += (v0.y + v1.y) + (v2.y + v3.y);
        acc.z += (v0.z + v1.z) + (v2.z + v3.z);
        acc.w += (v0.w + v1.w) + (v2.w + v3.w);
    }
    for (; i < end; i += 4) {
        float4 v = xe4[(size_t)elist[i] * 16 + q];
        acc.x += v.x; acc.y += v.y; acc.z += v.z; acc.w += v.w;
    }

    // reduce across the 4 row slots (lane bits 4,5)
    #pragma unroll
    for (int m = 16; m < 64; m <<= 1) {
        acc.x += __shfl_xor(acc.x, m);
        acc.y += __shfl_xor(acc.y, m);
        acc.z += __shfl_xor(acc.z, m);
        acc.w += __shfl_xor(acc.w, m);
    }
    if (sub == 0)
        ((float4*)agg)[(size_t)w * 16 + q] = acc;
}

// ---------- fallback atomic scatter (tiny ws) ------------------------------
__global__ __launch_bounds__(256)
void nb_scatter(const float* __restrict__ x_edge, const int* __restrict__ eidx,
                float* __restrict__ agg, int n_edges)
{
    long long t = (long long)blockIdx.x * 256 + threadIdx.x;
    int e = (int)(t >> 6);
    if (e >= n_edges) return;
    int d = (int)(t & 63);
    bool is64 = detect_i64(eidx, threadIdx.x & 63);
    int s, dd;
    if (is64) {
        s  = eidx[2 * (size_t)e];
        dd = eidx[2 * ((size_t)n_edges + (size_t)e)];
    } else {
        s  = eidx[e];
        dd = eidx[n_edges + e];
    }
    float v = x_edge[(size_t)e * D + d];
    unsafeAtomicAdd(&agg[(size_t)s * D + d], v);
    unsafeAtomicAdd(&agg[(size_t)dd * D + d], v);
}

// ---------------------------------------------------------------------------
// MLP: out[n] = relu(concat(x_node[n], agg[n]) @ W1 + b1) @ W2 + b2
// 1024 threads (16 waves/CU despite 1 block/CU). Weights in LDS; hidden
// mapping: lane j owns units {j, j+64} so all weight reads are consecutive
// b32 (2 lanes/bank = conflict-free). s_h overlays s_in (wave-private reuse).
// agg read from d_out, out written in place (row n touched only by its wave).
// ---------------------------------------------------------------------------
__global__ __launch_bounds__(MLPB, 1)
void nb_mlp(const float* __restrict__ x_node, const float* __restrict__ agg,
            const float* __restrict__ W1, const float* __restrict__ b1,
            const float* __restrict__ W2, const float* __restrict__ b2,
            float* __restrict__ out, int n_nodes)
{
    __shared__ float sW1[HID * HID];       // 64 KB, W1[k][j]
    __shared__ float sW2[HID * D];         // 32 KB, W2[h][j]
    __shared__ float sb1[HID];
    __shared__ float sb2[D];
    __shared__ float4 s_buf[WPB][128];     // 32 KB: inputs, then hidden (overlaid)

    {
        const float4* W14 = (const float4*)W1;
        float4* sW14 = (float4*)sW1;
        #pragma unroll
        for (int i = 0; i < 4; ++i)
            sW14[threadIdx.x + i * MLPB] = W14[threadIdx.x + i * MLPB];
        const float4* W24 = (const float4*)W2;
        float4* sW24 = (float4*)sW2;
        #pragma unroll
        for (int i = 0; i < 2; ++i)
            sW24[threadIdx.x + i * MLPB] = W24[threadIdx.x + i * MLPB];
        if (threadIdx.x < 128) sb1[threadIdx.x] = b1[threadIdx.x];
        else if (threadIdx.x < 192) sb2[threadIdx.x - 128] = b2[threadIdx.x - 128];
    }
    __syncthreads();

    const int wave = threadIdx.x >> 6;
    const int lane = threadIdx.x & 63;
    const int group = blockIdx.x * WPB + wave;
    const int ngroups = gridDim.x * WPB;
    const int nbatches = (n_nodes + NB - 1) / NB;

    for (int g = group; g < nbatches; g += ngroups) {
        const int n0 = g * NB;

        // ---- stage inputs: lane j provides k=j (x_node) and k=64+j (agg) ----
        float4 vx, va;
        #pragma unroll
        for (int b = 0; b < NB; ++b) {
            const int n = n0 + b;
            const bool ok = (n < n_nodes);
            ((float*)&vx)[b] = ok ? x_node[(size_t)n * D + lane] : 0.f;
            ((float*)&va)[b] = ok ? agg[(size_t)n * D + lane] : 0.f;
        }
        s_buf[wave][lane] = vx;
        s_buf[wave][64 + lane] = va;
        __builtin_amdgcn_wave_barrier();

        // ---- hidden layer: lane j -> units j and j+64, for 4 nodes ----
        const float bh0 = sb1[lane], bh1 = sb1[64 + lane];
        float a0[NB], a1[NB];
        #pragma unroll
        for (int b = 0; b < NB; ++b) { a0[b] = bh0; a1[b] = bh1; }

        #pragma unroll 4
        for (int k = 0; k < 128; ++k) {
            const float4 a = s_buf[wave][k];          // broadcast, 4 nodes
            const float w0 = sW1[k * HID + lane];     // unit j
            const float w1 = sW1[k * HID + 64 + lane];// unit j+64
            #pragma unroll
            for (int b = 0; b < NB; ++b) {
                a0[b] = fmaf(((const float*)&a)[b], w0, a0[b]);
                a1[b] = fmaf(((const float*)&a)[b], w1, a1[b]);
            }
        }
        float4 h0v, h1v;
        #pragma unroll
        for (int b = 0; b < NB; ++b) {
            ((float*)&h0v)[b] = fmaxf(a0[b], 0.f);
            ((float*)&h1v)[b] = fmaxf(a1[b], 0.f);
        }
        __builtin_amdgcn_wave_barrier();   // all s_buf reads done before overlay
        s_buf[wave][lane]      = h0v;      // hidden unit j
        s_buf[wave][64 + lane] = h1v;      // hidden unit j+64
        __builtin_amdgcn_wave_barrier();

        // ---- output layer: lane j -> out[j] for 4 nodes ----
        const float bo = sb2[lane];
        float o[NB];
        #pragma unroll
        for (int b = 0; b < NB; ++b) o[b] = bo;
        #pragma unroll 4
        for (int hh = 0; hh < 128; ++hh) {
            const float4 hv = s_buf[wave][hh];        // broadcast, 4 nodes
            const float wv = sW2[hh * D + lane];      // consecutive b32
            #pragma unroll
            for (int b = 0; b < NB; ++b)
                o[b] = fmaf(((const float*)&hv)[b], wv, o[b]);
        }
        #pragma unroll
        for (int b = 0; b < NB; ++b) {
            const int n = n0 + b;
            if (n < n_nodes) out[(size_t)n * D + lane] = o[b];
        }
    }
}

// ---------------------------------------------------------------------------
extern "C" void kernel_launch(void* const* d_in, const int* in_sizes, int n_in,
                              void* d_out, int out_size, void* d_ws, size_t ws_size,
                              hipStream_t stream)
{
    const float* x_node = (const float*)d_in[0];
    const float* x_edge = (const float*)d_in[1];
    const int*   eidx   = (const int*)d_in[2];
    const float* W1     = (const float*)d_in[3];
    const float* b1     = (const float*)d_in[4];
    const float* W2     = (const float*)d_in[5];
    const float* b2     = (const float*)d_in[6];
    float* out = (float*)d_out;

    const int n_nodes = in_sizes[0] / D;     // 50000
    const int n_edges = in_sizes[2] / 2;     // 800000
    const int E2 = 2 * n_edges;

    float* agg = out;   // agg lives in d_out; MLP rewrites rows in place

    // ws layout: offsets[N+1] | counts[N] | cursor[N] | bsum[256] | elist[2E] | nid[2E]
    const size_t base_words = (size_t)(n_nodes + 1) + n_nodes + n_nodes + 256 + E2;
    const size_t needB = base_words * 4;
    const size_t needA = (base_words + E2) * 4;

    if (ws_size >= needB) {
        const int use_nid = (ws_size >= needA) ? 1 : 0;
        int* offsets = (int*)d_ws;
        int* counts  = offsets + (n_nodes + 1);
        int* cursor  = counts + n_nodes;
        int* bsum    = cursor + n_nodes;
        int* elist   = bsum + 256;
        int* nid     = elist + E2;   // valid only if use_nid

        const int nscan = (n_nodes + 255) / 256;

        hipMemsetAsync(counts, 0, (size_t)n_nodes * 4, stream);
        csr_hist<<<(E2 + 255) / 256, 256, 0, stream>>>(eidx, counts, nid, use_nid, n_edges);
        csr_blocksum<<<nscan, 256, 0, stream>>>(counts, bsum, n_nodes);
        csr_scan_bsum<<<1, 256, 0, stream>>>(bsum, nscan);
        csr_scan_final<<<nscan, 256, 0, stream>>>(counts, bsum, offsets, cursor, n_nodes);

        const int n_windows = (n_nodes + (1 << WIN_SHIFT) - 1) >> WIN_SHIFT;  // 7
        csr_place_win<<<dim3(1024, n_windows), 256, 0, stream>>>(
            eidx, nid, use_nid, cursor, elist, n_edges);

        csr_gather4<<<(n_nodes * 64 + 255) / 256, 256, 0, stream>>>(
            x_edge, offsets, elist, agg, n_nodes);
    } else {
        hipMemsetAsync(agg, 0, (size_t)n_nodes * D * sizeof(float), stream);
        long long threads = (long long)n_edges * 64;
        nb_scatter<<<(int)((threads + 255) / 256), 256, 0, stream>>>(
            x_edge, eidx, agg, n_edges);
    }

    nb_mlp<<<256, MLPB, 0, stream>>>(x_node, agg, W1, b1, W2, b2, out, n_nodes);
}